// Round 9
// baseline (253.555 us; speedup 1.0000x reference)
//
#include <hip/hip_runtime.h>
#include <cstddef>
#include <cstdint>

#define B_DIM   2
#define S_LEN   2048
#define EMB     1024
#define NH      16
#define HD      64
#define QKV_N   3072
#define MROWS   (B_DIM * S_LEN)

using half8  = __attribute__((ext_vector_type(8))) _Float16;
using half4  = __attribute__((ext_vector_type(4))) _Float16;
using f32x4  = __attribute__((ext_vector_type(4))) float;

#if defined(__has_builtin)
#if __has_builtin(__builtin_amdgcn_global_load_lds)
#define HAS_GLL 1
#endif
#endif

__device__ __forceinline__ void stage16(const _Float16* g, _Float16* lds_base, int lane)
{
#ifdef HAS_GLL
    (void)lane;
    __builtin_amdgcn_global_load_lds(
        (const __attribute__((address_space(1))) unsigned int*)g,
        (__attribute__((address_space(3))) unsigned int*)lds_base, 16, 0, 0);
#else
    *(half8*)(lds_base + lane * 8) = *(const half8*)g;
#endif
}

// ---------------------------------------------------------------------------
// Weights-only prep: [0,3072) transpose w_attn; [3072,4096) transpose w_proj.
// ---------------------------------------------------------------------------
__global__ __launch_bounds__(256)
void prep_w(const float* __restrict__ w_attn, const float* __restrict__ w_proj,
            _Float16* __restrict__ wattn_t, _Float16* __restrict__ wproj_t)
{
    const int bid = blockIdx.x, t = threadIdx.x;
    __shared__ float T[32][33];
    const float* W; _Float16* Wt; int N, bx, by;
    if (bid < 3072) {
        bx = bid % 96; by = bid / 96; W = w_attn; Wt = wattn_t; N = QKV_N;
    } else {
        int t3 = bid - 3072; bx = t3 & 31; by = t3 >> 5; W = w_proj; Wt = wproj_t; N = EMB;
    }
    const int n0 = bx * 32, k0 = by * 32;
    const int r = t >> 3, c4 = (t & 7) * 4;
    float4 w = *(const float4*)(W + (size_t)(k0 + r) * N + n0 + c4);
    T[r][c4 + 0] = w.x; T[r][c4 + 1] = w.y;
    T[r][c4 + 2] = w.z; T[r][c4 + 3] = w.w;
    __syncthreads();
    half4 h = { (_Float16)T[c4 + 0][r], (_Float16)T[c4 + 1][r],
                (_Float16)T[c4 + 2][r], (_Float16)T[c4 + 3][r] };
    *(half4*)(Wt + (size_t)(n0 + r) * EMB + k0 + c4) = h;
}

// ---------------------------------------------------------------------------
// f16 MFMA GEMM, BK=64, GLL staging (B), XOR-swizzled LDS columns.
// A_F32: A staged from fp32 global via register cvt (BM must be 128).
// FUSE_VT: blocks with n0 >= 2*EMB write V transposed into vt[bh][d][s].
// ---------------------------------------------------------------------------
template <int MT, int MINW, bool OUT_F16, bool FUSE_VT, bool A_F32>
__global__ __launch_bounds__(256, MINW)
void hgemm_lds(const void* __restrict__ Xv, const _Float16* __restrict__ Wt,
               const float* __restrict__ bias, void* __restrict__ Cout,
               _Float16* __restrict__ vt, int M, int N, int K)
{
    constexpr int BM = MT * 32;
    constexpr int ACALLS = BM / 32;
    __shared__ _Float16 As[BM][64];
    __shared__ _Float16 Bs[128][64];

    const int tid  = threadIdx.x;
    const int wave = tid >> 6, lane = tid & 63;
    const int quad = lane >> 4, l15 = lane & 15;
    const int wm = (wave >> 1) * (MT * 16);
    const int wn = (wave & 1) * 64;
    const int m0 = blockIdx.y * BM, n0 = blockIdx.x * 128;

    const int srow = lane >> 3;
    const int scol = ((lane & 7) ^ srow) * 8;

    // A source (f16 GLL path)
    const _Float16* xg[ACALLS];
    if (!A_F32) {
        const _Float16* X = (const _Float16*)Xv;
#pragma unroll
        for (int c = 0; c < ACALLS; ++c)
            xg[c] = X + (size_t)(m0 + wave * (BM / 4) + c * 8 + srow) * K + scol;
    }
    // A source (fp32 register path): thread owns row r, k-half kh
    const float* Xf = (const float*)Xv;
    const int ar = tid >> 1, akh = (tid & 1) * 32;

    const _Float16* wg[4];
#pragma unroll
    for (int c = 0; c < 4; ++c)
        wg[c] = Wt + (size_t)(n0 + wave * 32 + c * 8 + srow) * K + scol;

    f32x4 acc[MT][4] = {};
    const int sx = l15 & 7;

    for (int k0 = 0; k0 < K; k0 += 64) {
        if (A_F32) {
            const float* src = Xf + (size_t)(m0 + ar) * K + k0 + akh;
            float4 f[8];
#pragma unroll
            for (int i = 0; i < 8; ++i) f[i] = *(const float4*)(src + i * 4);
#pragma unroll
            for (int g2 = 0; g2 < 4; ++g2) {
                half8 hh = { (_Float16)f[2 * g2].x, (_Float16)f[2 * g2].y,
                             (_Float16)f[2 * g2].z, (_Float16)f[2 * g2].w,
                             (_Float16)f[2 * g2 + 1].x, (_Float16)f[2 * g2 + 1].y,
                             (_Float16)f[2 * g2 + 1].z, (_Float16)f[2 * g2 + 1].w };
                const int g = (tid & 1) * 4 + g2;
                *(half8*)&As[ar][(g ^ (ar & 7)) * 8] = hh;
            }
        } else {
#pragma unroll
            for (int c = 0; c < ACALLS; ++c)
                stage16(xg[c] + k0, &As[wave * (BM / 4) + c * 8][0], lane);
        }
#pragma unroll
        for (int c = 0; c < 4; ++c)
            stage16(wg[c] + k0, &Bs[wave * 32 + c * 8][0], lane);
        __syncthreads();

#pragma unroll
        for (int cc = 0; cc < 2; ++cc) {
            half8 af[MT], bf[4];
#pragma unroll
            for (int mt = 0; mt < MT; ++mt)
                af[mt] = *(const half8*)&As[wm + mt * 16 + l15][(((cc * 4 + quad) ^ sx)) * 8];
#pragma unroll
            for (int nt = 0; nt < 4; ++nt)
                bf[nt] = *(const half8*)&Bs[wn + nt * 16 + l15][(((cc * 4 + quad) ^ sx)) * 8];
#pragma unroll
            for (int mt = 0; mt < MT; ++mt)
#pragma unroll
                for (int nt = 0; nt < 4; ++nt)
                    acc[mt][nt] = __builtin_amdgcn_mfma_f32_16x16x32_f16(
                        af[mt], bf[nt], acc[mt][nt], 0, 0, 0);
        }
        __syncthreads();
    }

    if (FUSE_VT && n0 >= 2 * EMB) {
#pragma unroll
        for (int nt = 0; nt < 4; ++nt) {
            const int c  = n0 + wn + nt * 16 + l15;
            const float bv = bias[c];
            const int vcol = c - 2 * EMB;
            const int hh = vcol >> 6, dd = vcol & 63;
#pragma unroll
            for (int mt = 0; mt < MT; ++mt) {
                const int r = m0 + wm + mt * 16 + quad * 4;
                const int bb = r >> 11, ss = r & 2047;
                half4 o = { (_Float16)(acc[mt][nt][0] + bv), (_Float16)(acc[mt][nt][1] + bv),
                            (_Float16)(acc[mt][nt][2] + bv), (_Float16)(acc[mt][nt][3] + bv) };
                *(half4*)(vt + ((size_t)(bb * NH + hh) * HD + dd) * S_LEN + ss) = o;
            }
        }
        return;
    }

#pragma unroll
    for (int nt = 0; nt < 4; ++nt) {
        const int c = n0 + wn + nt * 16 + l15;
        const float bv = bias[c];
#pragma unroll
        for (int mt = 0; mt < MT; ++mt)
#pragma unroll
            for (int reg = 0; reg < 4; ++reg) {
                const int r = m0 + wm + mt * 16 + quad * 4 + reg;
                const float v = acc[mt][nt][reg] + bv;
                if (OUT_F16)
                    ((_Float16*)Cout)[(size_t)r * N + c] = (_Float16)v;
                else
                    ((float*)Cout)[(size_t)r * N + c] = v;
            }
    }
}

// ---------------------------------------------------------------------------
// MFMA flash attention v8: paired q-tiles + kt-parity split across two
// 4-wave groups in a 512-thread block. Grid 512 -> 4096 waves (4/SIMD).
// Group g handles kt ≡ g (mod 2); partial (m,l,O) merged in LDS at the end.
// ---------------------------------------------------------------------------
__global__ __launch_bounds__(512, 4)
void attn_fa_mfma8(const _Float16* __restrict__ qkv,
                   const _Float16* __restrict__ vt,
                   _Float16* __restrict__ outh)
{
    __shared__ _Float16 smem[32768];   // 64 KB: Ks[2]:16KB each, Vs[2]:16KB each

    const int n   = blockIdx.x;
    const int xcd = n & 7, g4 = (n >> 3) & 3, j = n >> 5;
    const int bh  = xcd * 4 + g4;
    const int qta = j, qtb = 31 - j;
    const int b = bh >> 4, h = bh & 15;

    const int tid  = threadIdx.x;
    const int wave = tid >> 6, lane = tid & 63;
    const int grp  = wave >> 2, wl = wave & 3;
    const int quad = lane >> 4, l15 = lane & 15;
    const size_t row0 = (size_t)b * S_LEN;

    _Float16 (*Ks)[64]  = (_Float16(*)[64]) (smem + grp * 8192);
    _Float16 (*Vs)[128] = (_Float16(*)[128])(smem + 16384 + grp * 8192);

    const _Float16 qscale = (_Float16)0.0901684400555602f;
    half8 qfa[2], qfb[2];
    {
        const _Float16* qpa = qkv + (row0 + qta * 64 + wl * 16 + l15) * QKV_N + h * HD + quad * 8;
        const _Float16* qpb = qkv + (row0 + qtb * 64 + wl * 16 + l15) * QKV_N + h * HD + quad * 8;
#pragma unroll
        for (int c = 0; c < 2; ++c) {
            half8 qa = *(const half8*)(qpa + c * 32);
            half8 qb = *(const half8*)(qpb + c * 32);
#pragma unroll
            for (int j2 = 0; j2 < 8; ++j2) { qa[j2] *= qscale; qb[j2] *= qscale; }
            qfa[c] = qa; qfb[c] = qb;
        }
    }

    f32x4 o_a[4] = {}, o_b[4] = {};
    float m_a = -1e30f, l_a = 0.0f, m_b = -1e30f, l_b = 0.0f;

    const int ksrow = lane >> 3;
    const int kscol = ((lane & 7) ^ ksrow) * 8;
    const int vsrow = lane >> 4;
    const _Float16* vbase = vt + (size_t)bh * HD * S_LEN;
    const int sxk = l15 & 7;

    auto softmax_pack = [&](f32x4 (&st)[8], half4 (&pf)[8], float& m_i, float& l_i,
                            f32x4 (&o_acc)[4]) {
        float rm = fmaxf(fmaxf(st[0][0], st[0][1]), fmaxf(st[0][2], st[0][3]));
#pragma unroll
        for (int nt = 1; nt < 8; ++nt) {
            rm = fmaxf(rm, fmaxf(st[nt][0], st[nt][1]));
            rm = fmaxf(rm, fmaxf(st[nt][2], st[nt][3]));
        }
        rm = fmaxf(rm, __shfl_xor(rm, 16));
        rm = fmaxf(rm, __shfl_xor(rm, 32));
        const float mnew = fmaxf(m_i, rm);
        if (__ballot(mnew > m_i)) {
            const float alpha = __builtin_amdgcn_exp2f(m_i - mnew);
            l_i *= alpha;
#pragma unroll
            for (int dt = 0; dt < 4; ++dt)
#pragma unroll
                for (int reg = 0; reg < 4; ++reg) o_acc[dt][reg] *= alpha;
        }
        m_i = mnew;
        float rs = 0.0f;
#pragma unroll
        for (int nt = 0; nt < 8; ++nt) {
            float p0 = __builtin_amdgcn_exp2f(st[nt][0] - mnew);
            float p1 = __builtin_amdgcn_exp2f(st[nt][1] - mnew);
            float p2 = __builtin_amdgcn_exp2f(st[nt][2] - mnew);
            float p3 = __builtin_amdgcn_exp2f(st[nt][3] - mnew);
            rs += (p0 + p1) + (p2 + p3);
            pf[nt] = half4{ (_Float16)p0, (_Float16)p1, (_Float16)p2, (_Float16)p3 };
        }
        rs += __shfl_xor(rs, 16);
        rs += __shfl_xor(rs, 32);
        l_i += rs;
    };

    const int ktNa = (qta + 2) >> 1;     // 1..8
    const int ktNb = (qtb + 2) >> 1;     // 9..16 (ktNa + ktNb = 17)
    const int TMAX = (ktNb + 1) >> 1;    // uniform trips for both groups

    for (int i = 0; i < TMAX; ++i) {
        const int kt = grp + 2 * i;
        const bool valid = kt < ktNb;
        __syncthreads();
        if (valid) {
            const _Float16* kbase = qkv + (row0 + kt * 128) * QKV_N + EMB + h * HD;
#pragma unroll
            for (int c = 0; c < 4; ++c) {
                const int r0 = wl * 32 + c * 8;
                stage16(kbase + (size_t)(r0 + ksrow) * QKV_N + kscol, &Ks[r0][0], lane);
            }
#pragma unroll
            for (int c = 0; c < 4; ++c) {
                const int r0 = wl * 16 + c * 4;
                const int sgv = ((lane & 15) ^ (c * 4 + vsrow)) * 8;
                stage16(vbase + (size_t)(r0 + vsrow) * S_LEN + kt * 128 + sgv, &Vs[r0][0], lane);
            }
        }
        __syncthreads();
        if (!valid) continue;

        if (kt < ktNa) {
            f32x4 sa[8] = {}, sb[8] = {};
#pragma unroll
            for (int c = 0; c < 2; ++c)
#pragma unroll
                for (int nt = 0; nt < 8; ++nt) {
                    half8 kf = *(const half8*)&Ks[nt * 16 + l15][((c * 4 + quad) ^ sxk) * 8];
                    sa[nt] = __builtin_amdgcn_mfma_f32_16x16x32_f16(kf, qfa[c], sa[nt], 0, 0, 0);
                    sb[nt] = __builtin_amdgcn_mfma_f32_16x16x32_f16(kf, qfb[c], sb[nt], 0, 0, 0);
                }
            if (kt == ktNa - 1) {
                const int q = qta * 64 + wl * 16 + l15;
#pragma unroll
                for (int nt = 0; nt < 8; ++nt) {
                    const int ks = kt * 128 + nt * 16 + quad * 4;
#pragma unroll
                    for (int reg = 0; reg < 4; ++reg)
                        if (ks + reg > q) sa[nt][reg] = -1e30f;
                }
            }
            half4 pfa[8], pfb[8];
            softmax_pack(sa, pfa, m_a, l_a, o_a);
            softmax_pack(sb, pfb, m_b, l_b, o_b);
#pragma unroll
            for (int nt = 0; nt < 8; ++nt)
#pragma unroll
                for (int dt = 0; dt < 4; ++dt) {
                    const int pg = ((2 * nt + (quad >> 1)) ^ l15) * 8 + (quad & 1) * 4;
                    half4 vf = *(const half4*)&Vs[dt * 16 + l15][pg];
                    o_a[dt] = __builtin_amdgcn_mfma_f32_16x16x16f16(vf, pfa[nt], o_a[dt], 0, 0, 0);
                    o_b[dt] = __builtin_amdgcn_mfma_f32_16x16x16f16(vf, pfb[nt], o_b[dt], 0, 0, 0);
                }
        } else {
            f32x4 sb[8] = {};
#pragma unroll
            for (int c = 0; c < 2; ++c)
#pragma unroll
                for (int nt = 0; nt < 8; ++nt) {
                    half8 kf = *(const half8*)&Ks[nt * 16 + l15][((c * 4 + quad) ^ sxk) * 8];
                    sb[nt] = __builtin_amdgcn_mfma_f32_16x16x32_f16(kf, qfb[c], sb[nt], 0, 0, 0);
                }
            if (kt == ktNb - 1) {
                const int q = qtb * 64 + wl * 16 + l15;
#pragma unroll
                for (int nt = 0; nt < 8; ++nt) {
                    const int ks = kt * 128 + nt * 16 + quad * 4;
#pragma unroll
                    for (int reg = 0; reg < 4; ++reg)
                        if (ks + reg > q) sb[nt][reg] = -1e30f;
                }
            }
            half4 pfb[8];
            softmax_pack(sb, pfb, m_b, l_b, o_b);
#pragma unroll
            for (int nt = 0; nt < 8; ++nt)
#pragma unroll
                for (int dt = 0; dt < 4; ++dt) {
                    const int pg = ((2 * nt + (quad >> 1)) ^ l15) * 8 + (quad & 1) * 4;
                    half4 vf = *(const half4*)&Vs[dt * 16 + l15][pg];
                    o_b[dt] = __builtin_amdgcn_mfma_f32_16x16x16f16(vf, pfb[nt], o_b[dt], 0, 0, 0);
                }
        }
    }

    // ---- cross-group merge via LDS (stride 40 floats, conflict-light) ----
    float* mb = (float*)smem;
    const int gl = tid & 255;
    __syncthreads();
    if (grp == 1) {
        float* p = mb + gl * 40;
#pragma unroll
        for (int dt = 0; dt < 4; ++dt) { *(f32x4*)(p + dt * 4)      = o_a[dt]; }
#pragma unroll
        for (int dt = 0; dt < 4; ++dt) { *(f32x4*)(p + 16 + dt * 4) = o_b[dt]; }
        p[32] = m_a; p[33] = l_a; p[34] = m_b; p[35] = l_b;
    }
    __syncthreads();
    if (grp == 0) {
        const float* p = mb + gl * 40;
        {
            const float m1 = p[32], l1 = p[33];
            const float m = fmaxf(m_a, m1);
            const float a0 = __builtin_amdgcn_exp2f(m_a - m);
            const float a1 = __builtin_amdgcn_exp2f(m1 - m);
            const float inv = 1.0f / (l_a * a0 + l1 * a1);
            const size_t r = row0 + qta * 64 + wl * 16 + l15;
#pragma unroll
            for (int dt = 0; dt < 4; ++dt) {
                f32x4 o1 = *(const f32x4*)(p + dt * 4);
                half4 o = { (_Float16)((o_a[dt][0] * a0 + o1[0] * a1) * inv),
                            (_Float16)((o_a[dt][1] * a0 + o1[1] * a1) * inv),
                            (_Float16)((o_a[dt][2] * a0 + o1[2] * a1) * inv),
                            (_Float16)((o_a[dt][3] * a0 + o1[3] * a1) * inv) };
                *(half4*)(outh + r * EMB + h * HD + dt * 16 + quad * 4) = o;
            }
        }
        {
            const float m1 = p[34], l1 = p[35];
            const float m = fmaxf(m_b, m1);
            const float a0 = __builtin_amdgcn_exp2f(m_b - m);
            const float a1 = __builtin_amdgcn_exp2f(m1 - m);
            const float inv = 1.0f / (l_b * a0 + l1 * a1);
            const size_t r = row0 + qtb * 64 + wl * 16 + l15;
#pragma unroll
            for (int dt = 0; dt < 4; ++dt) {
                f32x4 o1 = *(const f32x4*)(p + 16 + dt * 4);
                half4 o = { (_Float16)((o_b[dt][0] * a0 + o1[0] * a1) * inv),
                            (_Float16)((o_b[dt][1] * a0 + o1[1] * a1) * inv),
                            (_Float16)((o_b[dt][2] * a0 + o1[2] * a1) * inv),
                            (_Float16)((o_b[dt][3] * a0 + o1[3] * a1) * inv) };
                *(half4*)(outh + r * EMB + h * HD + dt * 16 + quad * 4) = o;
            }
        }
    }
}

// ---------------------------------------------------------------------------
extern "C" void kernel_launch(void* const* d_in, const int* in_sizes, int n_in,
                              void* d_out, int out_size, void* d_ws, size_t ws_size,
                              hipStream_t stream)
{
    const float* hidden = (const float*)d_in[0];
    const float* w_attn = (const float*)d_in[1];
    const float* b_attn = (const float*)d_in[2];
    const float* w_proj = (const float*)d_in[3];
    const float* b_proj = (const float*)d_in[4];

    _Float16* wattn_t = (_Float16*)d_ws;                         // 3M
    _Float16* wproj_t = wattn_t + (size_t)EMB * QKV_N;           // 1M
    _Float16* qkv_h   = wproj_t + (size_t)EMB * EMB;             // 12M
    _Float16* attn_h  = qkv_h + (size_t)MROWS * QKV_N;           // 4M
    _Float16* vt      = attn_h + (size_t)MROWS * EMB;            // 4M

    prep_w<<<4096, 256, 0, stream>>>(w_attn, w_proj, wattn_t, wproj_t);

    hgemm_lds<4, 3, true, true, true><<<dim3(QKV_N / 128, MROWS / 128), 256, 0, stream>>>(
        hidden, wattn_t, b_attn, qkv_h, vt, MROWS, QKV_N, EMB);

    attn_fa_mfma8<<<dim3(512), 512, 0, stream>>>(qkv_h, vt, attn_h);

    hgemm_lds<2, 4, false, false, false><<<dim3(EMB / 128, MROWS / 64), 256, 0, stream>>>(
        attn_h, wproj_t, b_proj, d_out, nullptr, MROWS, EMB, EMB);
}